// Round 2
// baseline (5679.457 us; speedup 1.0000x reference)
//
#include <hip/hip_runtime.h>
#include <cstdint>

#define NN 50000
#define NE 800000
#define NEF (NE + NN)
#define LAYERS 3
#define NEG_SLOPE 0.2f

// ---------------- sort-by-dst machinery (runs once per call) ----------------

__global__ void hist_kernel(const int* __restrict__ ei, int* __restrict__ cnt) {
  int e = blockIdx.x * blockDim.x + threadIdx.x;
  if (e < NE) atomicAdd(&cnt[ei[NE + e]], 1);
}

// exclusive scan of (cnt[i]+1) over NN elements, single 1024-thread block
__global__ void scan_kernel(const int* __restrict__ cnt, int* __restrict__ offs) {
  __shared__ int lds[1024];
  __shared__ int carry_s;
  int t = threadIdx.x;
  if (t == 0) carry_s = 0;
  __syncthreads();
  for (int base = 0; base < NN; base += 1024) {
    int i = base + t;
    int v = (i < NN) ? (cnt[i] + 1) : 0;   // +1 = self loop
    lds[t] = v;
    __syncthreads();
    for (int off = 1; off < 1024; off <<= 1) {
      int y = (t >= off) ? lds[t - off] : 0;
      __syncthreads();
      lds[t] += y;
      __syncthreads();
    }
    if (i < NN) offs[i] = carry_s + lds[t] - v;
    __syncthreads();
    if (t == 1023) carry_s += lds[1023];
    __syncthreads();
  }
  if (t == 0) offs[NN] = carry_s;
}

__global__ void scatter_kernel(const int* __restrict__ ei, const int* __restrict__ offs,
                               int* __restrict__ fill, int* __restrict__ seid, int* __restrict__ ssrc) {
  int e = blockIdx.x * blockDim.x + threadIdx.x;
  if (e >= NEF) return;
  int s, d;
  if (e < NE) { s = ei[e]; d = ei[NE + e]; }
  else        { s = d = e - NE; }
  int pos = offs[d] + atomicAdd(&fill[d], 1);
  seid[pos] = e;
  ssrc[pos] = s;
}

// loop_attr[n] = mean of edge_attr over original in-edges of n (0 if none)
__global__ void loopattr_kernel(const float* __restrict__ eattr, const int* __restrict__ offs,
                                const int* __restrict__ seid, float* __restrict__ lattr) {
  int wv = threadIdx.x >> 6, lane = threadIdx.x & 63;
  int n = blockIdx.x * 4 + wv;
  if (n >= NN) return;
  int beg = offs[n], end = offs[n + 1];
  float acc = 0.f;
  int c = 0;
  for (int i = beg; i < end; ++i) {
    int eid = seid[i];
    if (eid < NE) { acc += eattr[(size_t)eid * 64 + lane]; c++; }
  }
  lattr[n * 64 + lane] = acc / (float)(c > 0 ? c : 1);
}

// ---------------- per-layer kernels ----------------

// xl = x@Wl + bl ; xr = x@Wr + br    (x: [NN,256], W: [256,256])
__global__ void __launch_bounds__(256) node_gemm_kernel(
    const float* __restrict__ x, const float* __restrict__ Wl, const float* __restrict__ bl,
    const float* __restrict__ Wr, const float* __restrict__ br,
    float* __restrict__ xl, float* __restrict__ xr) {
  __shared__ float xs[16][256];
  int t = threadIdx.x;
  int row0 = blockIdx.x * 16;
  #pragma unroll
  for (int j = 0; j < 16; ++j) xs[j][t] = x[(row0 + j) * 256 + t];
  __syncthreads();
  float aL[16], aR[16];
  #pragma unroll
  for (int r = 0; r < 16; ++r) { aL[r] = 0.f; aR[r] = 0.f; }
  for (int k4 = 0; k4 < 64; ++k4) {
    int k = 4 * k4;
    float l0 = Wl[(k + 0) * 256 + t], l1 = Wl[(k + 1) * 256 + t];
    float l2 = Wl[(k + 2) * 256 + t], l3 = Wl[(k + 3) * 256 + t];
    float r0 = Wr[(k + 0) * 256 + t], r1 = Wr[(k + 1) * 256 + t];
    float r2 = Wr[(k + 2) * 256 + t], r3 = Wr[(k + 3) * 256 + t];
    #pragma unroll
    for (int r = 0; r < 16; ++r) {
      float4 xv = *reinterpret_cast<const float4*>(&xs[r][k]);
      aL[r] += xv.x * l0 + xv.y * l1 + xv.z * l2 + xv.w * l3;
      aR[r] += xv.x * r0 + xv.y * r1 + xv.z * r2 + xv.w * r3;
    }
  }
  float bL = bl[t], bR = br[t];
  #pragma unroll
  for (int r = 0; r < 16; ++r) {
    xl[(row0 + r) * 256 + t] = aL[r] + bL;
    xr[(row0 + r) * 256 + t] = aR[r] + bR;
  }
}

// Fused: ee = eattr@We (on the fly), m = ee + xl[src] + xr[dst],
// logits[e,h] = sum_c leaky(m)*att[h,c].  64 edges/block; 2 column-halves.
__global__ void __launch_bounds__(256) edge_logits_kernel(
    const float* __restrict__ eattr, const float* __restrict__ lattr,
    const int* __restrict__ ei, const float* __restrict__ We,
    const float* __restrict__ att, const float* __restrict__ xl,
    const float* __restrict__ xr, float* __restrict__ logits) {
  __shared__ float ea_s[64][68];   // [edge_local][k], padded
  __shared__ float we_s[64][132];  // [k][c_local], stride 132 -> conflict-free column reads
  __shared__ float att_s[4][64];
  int t = threadIdx.x, lane = t & 63, wv = t >> 6;
  int e0 = blockIdx.x * 64;

  att_s[t >> 6][t & 63] = att[t];

  #pragma unroll
  for (int jj = 0; jj < 4; ++jj) {
    int idx = t + 256 * jj;          // 1024 float4 = 64 edges x 64 dims
    int row = idx >> 4, c4 = idx & 15;
    int e = e0 + row;
    float4 v = make_float4(0.f, 0.f, 0.f, 0.f);
    if (e < NEF) {
      const float* p = (e < NE) ? (eattr + (size_t)e * 64) : (lattr + (size_t)(e - NE) * 64);
      v = *reinterpret_cast<const float4*>(p + c4 * 4);
    }
    *reinterpret_cast<float4*>(&ea_s[row][c4 * 4]) = v;
  }

  for (int half = 0; half < 2; ++half) {
    __syncthreads();
    #pragma unroll
    for (int jj = 0; jj < 8; ++jj) {
      int idx = t + 256 * jj;        // 2048 float4 = 64 k x 128 cols
      int c4 = idx & 31, k = idx >> 5;
      float4 v = *reinterpret_cast<const float4*>(We + k * 256 + half * 128 + c4 * 4);
      we_s[k][c4 * 4 + 0] = v.x;
      we_s[k][c4 * 4 + 1] = v.y;
      we_s[k][c4 * 4 + 2] = v.z;
      we_s[k][c4 * 4 + 3] = v.w;
    }
    __syncthreads();

    float acc0[16], acc1[16];
    #pragma unroll
    for (int i = 0; i < 16; ++i) { acc0[i] = 0.f; acc1[i] = 0.f; }
    for (int k4 = 0; k4 < 16; ++k4) {
      int k = 4 * k4;
      float wa0 = we_s[k + 0][lane], wa1 = we_s[k + 1][lane];
      float wa2 = we_s[k + 2][lane], wa3 = we_s[k + 3][lane];
      float wb0 = we_s[k + 0][64 + lane], wb1 = we_s[k + 1][64 + lane];
      float wb2 = we_s[k + 2][64 + lane], wb3 = we_s[k + 3][64 + lane];
      #pragma unroll
      for (int i = 0; i < 16; ++i) {
        float4 a = *reinterpret_cast<const float4*>(&ea_s[wv * 16 + i][k]);
        acc0[i] += a.x * wa0 + a.y * wa1 + a.z * wa2 + a.w * wa3;
        acc1[i] += a.x * wb0 + a.y * wb1 + a.z * wb2 + a.w * wb3;
      }
    }

    int h0 = half * 2;
    float attA = att_s[h0][lane], attB = att_s[h0 + 1][lane];
    #pragma unroll
    for (int i = 0; i < 16; ++i) {
      int e = e0 + wv * 16 + i;
      float v0 = 0.f, v1 = 0.f;
      if (e < NEF) {
        int s, d;
        if (e < NE) { s = ei[e]; d = ei[NE + e]; }
        else        { s = d = e - NE; }
        int c = half * 128 + lane;
        float m0 = acc0[i] + xl[s * 256 + c] + xr[d * 256 + c];
        float m1 = acc1[i] + xl[s * 256 + c + 64] + xr[d * 256 + c + 64];
        m0 = (m0 > 0.f) ? m0 : NEG_SLOPE * m0;
        m1 = (m1 > 0.f) ? m1 : NEG_SLOPE * m1;
        v0 = m0 * attA;
        v1 = m1 * attB;
      }
      #pragma unroll
      for (int off = 32; off > 0; off >>= 1) {
        v0 += __shfl_xor(v0, off);
        v1 += __shfl_xor(v1, off);
      }
      if (e < NEF && lane == 0) {
        logits[e * 4 + h0]     = v0;
        logits[e * 4 + h0 + 1] = v1;
      }
    }
  }
}

// Per-node segment softmax + weighted aggregation (+bias). One block per node.
__global__ void __launch_bounds__(256) node_aggr_kernel(
    const float* __restrict__ logits, const float* __restrict__ xl,
    const int* __restrict__ offs, const int* __restrict__ seid,
    const int* __restrict__ ssrc, const float* __restrict__ bias,
    float* __restrict__ out) {
  int n = blockIdx.x;
  int t = threadIdx.x;
  int h = t >> 6;
  int beg = offs[n], end = offs[n + 1];
  float mx = -1e30f;
  for (int i = beg; i < end; ++i) mx = fmaxf(mx, logits[seid[i] * 4 + h]);
  float den = 0.f;
  for (int i = beg; i < end; ++i) den += expf(logits[seid[i] * 4 + h] - mx);
  float inv = 1.0f / den;
  float acc = 0.f;
  for (int i = beg; i < end; ++i) {
    float a = expf(logits[seid[i] * 4 + h] - mx) * inv;
    acc += a * xl[ssrc[i] * 256 + t];
  }
  out[n * 256 + t] = acc + bias[t];
}

// ---------------- host launcher ----------------

extern "C" void kernel_launch(void* const* d_in, const int* in_sizes, int n_in,
                              void* d_out, int out_size, void* d_ws, size_t ws_size,
                              hipStream_t stream) {
  (void)in_sizes; (void)n_in; (void)out_size; (void)ws_size;
  const float* x      = (const float*)d_in[0];
  const int* ei       = (const int*)d_in[1];
  const float* eattr  = (const float*)d_in[2];
  const float* Wl     = (const float*)d_in[3];
  const float* bl     = (const float*)d_in[4];
  const float* Wr     = (const float*)d_in[5];
  const float* br     = (const float*)d_in[6];
  const float* We     = (const float*)d_in[7];
  const float* att    = (const float*)d_in[8];
  const float* bias   = (const float*)d_in[9];

  size_t off = 0;
  char* base = (char*)d_ws;
  auto alloc = [&](size_t bytes) { void* p = base + off; off += (bytes + 255) & ~(size_t)255; return p; };
  float* xl     = (float*)alloc((size_t)NN * 256 * 4);
  float* xr     = (float*)alloc((size_t)NN * 256 * 4);
  float* bufA   = (float*)alloc((size_t)NN * 256 * 4);
  float* bufB   = (float*)alloc((size_t)NN * 256 * 4);
  float* logits = (float*)alloc((size_t)NEF * 4 * 4);
  float* lattr  = (float*)alloc((size_t)NN * 64 * 4);
  int* seid     = (int*)alloc((size_t)NEF * 4);
  int* ssrc     = (int*)alloc((size_t)NEF * 4);
  int* offs     = (int*)alloc((size_t)(NN + 1) * 4);
  int* cnt      = (int*)alloc((size_t)NN * 4);
  int* fill     = (int*)alloc((size_t)NN * 4);

  hipMemsetAsync(cnt, 0, (size_t)NN * 4, stream);
  hipMemsetAsync(fill, 0, (size_t)NN * 4, stream);

  hist_kernel<<<(NE + 255) / 256, 256, 0, stream>>>(ei, cnt);
  scan_kernel<<<1, 1024, 0, stream>>>(cnt, offs);
  scatter_kernel<<<(NEF + 255) / 256, 256, 0, stream>>>(ei, offs, fill, seid, ssrc);
  loopattr_kernel<<<(NN + 3) / 4, 256, 0, stream>>>(eattr, offs, seid, lattr);

  const float* xin = x;
  float* louts[3] = { bufA, bufB, (float*)d_out };
  for (int l = 0; l < LAYERS; ++l) {
    node_gemm_kernel<<<NN / 16, 256, 0, stream>>>(
        xin, Wl + (size_t)l * 256 * 256, bl + l * 256,
        Wr + (size_t)l * 256 * 256, br + l * 256, xl, xr);
    edge_logits_kernel<<<(NEF + 63) / 64, 256, 0, stream>>>(
        eattr, lattr, ei, We + (size_t)l * 64 * 256, att + l * 256, xl, xr, logits);
    node_aggr_kernel<<<NN, 256, 0, stream>>>(
        logits, xl, offs, seid, ssrc, bias + l * 256, louts[l]);
    xin = louts[l];
  }
}

// Round 3
// 3484.190 us; speedup vs baseline: 1.6301x; 1.6301x over previous
//
#include <hip/hip_runtime.h>
#include <cstdint>

#define NN 50000
#define NE 800000
#define NEF (NE + NN)
#define LAYERS 3
#define NEG_SLOPE 0.2f

// ---------------- sort-by-dst machinery (runs once per call) ----------------

__global__ void hist_kernel(const int* __restrict__ ei, int* __restrict__ cnt) {
  int e = blockIdx.x * blockDim.x + threadIdx.x;
  if (e < NE) atomicAdd(&cnt[ei[NE + e]], 1);
}

// exclusive scan of (cnt[i]+1) over NN elements, single 1024-thread block
__global__ void scan_kernel(const int* __restrict__ cnt, int* __restrict__ offs) {
  __shared__ int lds[1024];
  __shared__ int carry_s;
  int t = threadIdx.x;
  if (t == 0) carry_s = 0;
  __syncthreads();
  for (int base = 0; base < NN; base += 1024) {
    int i = base + t;
    int v = (i < NN) ? (cnt[i] + 1) : 0;   // +1 = self loop
    lds[t] = v;
    __syncthreads();
    for (int off = 1; off < 1024; off <<= 1) {
      int y = (t >= off) ? lds[t - off] : 0;
      __syncthreads();
      lds[t] += y;
      __syncthreads();
    }
    if (i < NN) offs[i] = carry_s + lds[t] - v;
    __syncthreads();
    if (t == 1023) carry_s += lds[1023];
    __syncthreads();
  }
  if (t == 0) offs[NN] = carry_s;
}

__global__ void scatter_kernel(const int* __restrict__ ei, const int* __restrict__ offs,
                               int* __restrict__ fill, int* __restrict__ seid, int* __restrict__ ssrc) {
  int e = blockIdx.x * blockDim.x + threadIdx.x;
  if (e >= NEF) return;
  int s, d;
  if (e < NE) { s = ei[e]; d = ei[NE + e]; }
  else        { s = d = e - NE; }
  int pos = offs[d] + atomicAdd(&fill[d], 1);
  seid[pos] = e;
  ssrc[pos] = s;
}

// loop_attr[n] = mean of edge_attr over original in-edges of n (0 if none)
__global__ void loopattr_kernel(const float* __restrict__ eattr, const int* __restrict__ offs,
                                const int* __restrict__ seid, float* __restrict__ lattr) {
  int wv = threadIdx.x >> 6, lane = threadIdx.x & 63;
  int n = blockIdx.x * 4 + wv;
  if (n >= NN) return;
  int beg = offs[n], end = offs[n + 1];
  float acc = 0.f;
  int c = 0;
  for (int i = beg; i < end; ++i) {
    int eid = seid[i];
    if (eid < NE) { acc += eattr[(size_t)eid * 64 + lane]; c++; }
  }
  lattr[n * 64 + lane] = acc / (float)(c > 0 ? c : 1);
}

// ---------------- per-layer kernels ----------------

// xl = x@Wl + bl ; xr = x@Wr + br    (x: [NN,256], W: [256,256])
__global__ void __launch_bounds__(256) node_gemm_kernel(
    const float* __restrict__ x, const float* __restrict__ Wl, const float* __restrict__ bl,
    const float* __restrict__ Wr, const float* __restrict__ br,
    float* __restrict__ xl, float* __restrict__ xr) {
  __shared__ float xs[16][256];
  int t = threadIdx.x;
  int row0 = blockIdx.x * 16;
  #pragma unroll
  for (int j = 0; j < 16; ++j) xs[j][t] = x[(row0 + j) * 256 + t];
  __syncthreads();
  float aL[16], aR[16];
  #pragma unroll
  for (int r = 0; r < 16; ++r) { aL[r] = 0.f; aR[r] = 0.f; }
  for (int k4 = 0; k4 < 64; ++k4) {
    int k = 4 * k4;
    float l0 = Wl[(k + 0) * 256 + t], l1 = Wl[(k + 1) * 256 + t];
    float l2 = Wl[(k + 2) * 256 + t], l3 = Wl[(k + 3) * 256 + t];
    float r0 = Wr[(k + 0) * 256 + t], r1 = Wr[(k + 1) * 256 + t];
    float r2 = Wr[(k + 2) * 256 + t], r3 = Wr[(k + 3) * 256 + t];
    #pragma unroll
    for (int r = 0; r < 16; ++r) {
      float4 xv = *reinterpret_cast<const float4*>(&xs[r][k]);
      aL[r] += xv.x * l0 + xv.y * l1 + xv.z * l2 + xv.w * l3;
      aR[r] += xv.x * r0 + xv.y * r1 + xv.z * r2 + xv.w * r3;
    }
  }
  float bL = bl[t], bR = br[t];
  #pragma unroll
  for (int r = 0; r < 16; ++r) {
    xl[(row0 + r) * 256 + t] = aL[r] + bL;
    xr[(row0 + r) * 256 + t] = aR[r] + bR;
  }
}

// Fused: ee = eattr@We (on the fly), m = ee + xl[src] + xr[dst],
// logits[e,h] = sum_c leaky(m)*att[h,c].  64 edges/block; 2 column-halves.
// v2: lane owns channel PAIR (c0 = half*128 + 2*lane) -> float2 gathers;
//     butterfly shuffles replaced by per-wave LDS partial buffer + flat row-sum.
__global__ void __launch_bounds__(256) edge_logits_kernel(
    const float* __restrict__ eattr, const float* __restrict__ lattr,
    const int* __restrict__ ei, const float* __restrict__ We,
    const float* __restrict__ att, const float* __restrict__ xl,
    const float* __restrict__ xr, float* __restrict__ logits) {
  __shared__ float ea_s[64][68];   // [edge_local][k], padded
  __shared__ float we_s[64][132];  // [k][c_local]; reused as partial buffer in tail
  __shared__ float att_s[256];
  __shared__ int sidx[64], didx[64];
  int t = threadIdx.x, lane = t & 63, wv = t >> 6;
  int e0 = blockIdx.x * 64;

  att_s[t] = att[t];
  if (t < 128) {
    int r = t & 63;
    int e = e0 + r;
    int v = 0;
    if (e < NE)       v = ei[(t < 64) ? e : (NE + e)];
    else if (e < NEF) v = e - NE;
    if (t < 64) sidx[r] = v; else didx[r] = v;
  }

  #pragma unroll
  for (int jj = 0; jj < 4; ++jj) {
    int idx = t + 256 * jj;          // 1024 float4 = 64 edges x 64 dims
    int row = idx >> 4, c4 = idx & 15;
    int e = e0 + row;
    float4 v = make_float4(0.f, 0.f, 0.f, 0.f);
    if (e < NEF) {
      const float* p = (e < NE) ? (eattr + (size_t)e * 64) : (lattr + (size_t)(e - NE) * 64);
      v = *reinterpret_cast<const float4*>(p + c4 * 4);
    }
    *reinterpret_cast<float4*>(&ea_s[row][c4 * 4]) = v;
  }

  for (int half = 0; half < 2; ++half) {
    __syncthreads();
    #pragma unroll
    for (int jj = 0; jj < 8; ++jj) {
      int idx = t + 256 * jj;        // 2048 float4 = 64 k x 128 cols
      int c4 = idx & 31, k = idx >> 5;
      float4 v = *reinterpret_cast<const float4*>(We + k * 256 + half * 128 + c4 * 4);
      we_s[k][c4 * 4 + 0] = v.x;
      we_s[k][c4 * 4 + 1] = v.y;
      we_s[k][c4 * 4 + 2] = v.z;
      we_s[k][c4 * 4 + 3] = v.w;
    }
    __syncthreads();

    float acc0[16], acc1[16];
    #pragma unroll
    for (int i = 0; i < 16; ++i) { acc0[i] = 0.f; acc1[i] = 0.f; }
    for (int k4 = 0; k4 < 16; ++k4) {
      int k = 4 * k4;
      float2 w0 = *reinterpret_cast<const float2*>(&we_s[k + 0][2 * lane]);
      float2 w1 = *reinterpret_cast<const float2*>(&we_s[k + 1][2 * lane]);
      float2 w2 = *reinterpret_cast<const float2*>(&we_s[k + 2][2 * lane]);
      float2 w3 = *reinterpret_cast<const float2*>(&we_s[k + 3][2 * lane]);
      #pragma unroll
      for (int i = 0; i < 16; ++i) {
        float4 a = *reinterpret_cast<const float4*>(&ea_s[wv * 16 + i][k]);
        acc0[i] += a.x * w0.x + a.y * w1.x + a.z * w2.x + a.w * w3.x;
        acc1[i] += a.x * w0.y + a.y * w1.y + a.z * w2.y + a.w * w3.y;
      }
    }

    // tail: gathers + leaky + att partials into per-wave LDS scratch (reuses we_s)
    __syncthreads();   // all waves done reading we_s before clobbering it
    float* part = &we_s[0][0] + wv * (16 * 68);
    int c0 = half * 128 + 2 * lane;
    float aA = att_s[c0], aB = att_s[c0 + 1];
    float aA5 = aA * NEG_SLOPE, aB5 = aB * NEG_SLOPE;
    #pragma unroll
    for (int i = 0; i < 16; ++i) {
      int r = wv * 16 + i;
      int s = sidx[r], d = didx[r];
      float2 gl = *reinterpret_cast<const float2*>(&xl[(size_t)s * 256 + c0]);
      float2 gr = *reinterpret_cast<const float2*>(&xr[(size_t)d * 256 + c0]);
      float m0 = acc0[i] + gl.x + gr.x;
      float m1 = acc1[i] + gl.y + gr.y;
      float v = m0 * (m0 > 0.f ? aA : aA5) + m1 * (m1 > 0.f ? aB : aB5);
      part[i * 68 + lane] = v;
    }
    // flat reduce: 32 outputs (16 edges x 2 heads), one per low lane
    if (lane < 32) {
      int oi = lane >> 1, hh = lane & 1;
      const float* row = part + oi * 68 + hh * 32;
      float4 s4 = make_float4(0.f, 0.f, 0.f, 0.f);
      #pragma unroll
      for (int j = 0; j < 8; ++j) {
        float4 v = *reinterpret_cast<const float4*>(row + 4 * j);
        s4.x += v.x; s4.y += v.y; s4.z += v.z; s4.w += v.w;
      }
      float sum = (s4.x + s4.y) + (s4.z + s4.w);
      int e = e0 + wv * 16 + oi;
      if (e < NEF) logits[e * 4 + half * 2 + hh] = sum;
    }
  }
}

// Per-node segment softmax + weighted aggregation (+bias). One block per node.
// v2: denom folded into the accumulation pass (2 sweeps instead of 3).
__global__ void __launch_bounds__(256) node_aggr_kernel(
    const float* __restrict__ logits, const float* __restrict__ xl,
    const int* __restrict__ offs, const int* __restrict__ seid,
    const int* __restrict__ ssrc, const float* __restrict__ bias,
    float* __restrict__ out) {
  int n = blockIdx.x;
  int t = threadIdx.x;
  int h = t >> 6;
  int beg = offs[n], end = offs[n + 1];
  float mx = -1e30f;
  for (int i = beg; i < end; ++i) mx = fmaxf(mx, logits[seid[i] * 4 + h]);
  float den = 0.f;
  float acc = 0.f;
  for (int i = beg; i < end; ++i) {
    float a = expf(logits[seid[i] * 4 + h] - mx);
    den += a;
    acc += a * xl[(size_t)ssrc[i] * 256 + t];
  }
  out[n * 256 + t] = acc / den + bias[t];
}

// ---------------- host launcher ----------------

extern "C" void kernel_launch(void* const* d_in, const int* in_sizes, int n_in,
                              void* d_out, int out_size, void* d_ws, size_t ws_size,
                              hipStream_t stream) {
  (void)in_sizes; (void)n_in; (void)out_size; (void)ws_size;
  const float* x      = (const float*)d_in[0];
  const int* ei       = (const int*)d_in[1];
  const float* eattr  = (const float*)d_in[2];
  const float* Wl     = (const float*)d_in[3];
  const float* bl     = (const float*)d_in[4];
  const float* Wr     = (const float*)d_in[5];
  const float* br     = (const float*)d_in[6];
  const float* We     = (const float*)d_in[7];
  const float* att    = (const float*)d_in[8];
  const float* bias   = (const float*)d_in[9];

  size_t off = 0;
  char* base = (char*)d_ws;
  auto alloc = [&](size_t bytes) { void* p = base + off; off += (bytes + 255) & ~(size_t)255; return p; };
  float* xl     = (float*)alloc((size_t)NN * 256 * 4);
  float* xr     = (float*)alloc((size_t)NN * 256 * 4);
  float* bufA   = (float*)alloc((size_t)NN * 256 * 4);
  float* bufB   = (float*)alloc((size_t)NN * 256 * 4);
  float* logits = (float*)alloc((size_t)NEF * 4 * 4);
  float* lattr  = (float*)alloc((size_t)NN * 64 * 4);
  int* seid     = (int*)alloc((size_t)NEF * 4);
  int* ssrc     = (int*)alloc((size_t)NEF * 4);
  int* offs     = (int*)alloc((size_t)(NN + 1) * 4);
  int* cnt      = (int*)alloc((size_t)NN * 4);
  int* fill     = (int*)alloc((size_t)NN * 4);

  hipMemsetAsync(cnt, 0, (size_t)NN * 4, stream);
  hipMemsetAsync(fill, 0, (size_t)NN * 4, stream);

  hist_kernel<<<(NE + 255) / 256, 256, 0, stream>>>(ei, cnt);
  scan_kernel<<<1, 1024, 0, stream>>>(cnt, offs);
  scatter_kernel<<<(NEF + 255) / 256, 256, 0, stream>>>(ei, offs, fill, seid, ssrc);
  loopattr_kernel<<<(NN + 3) / 4, 256, 0, stream>>>(eattr, offs, seid, lattr);

  const float* xin = x;
  float* louts[3] = { bufA, bufB, (float*)d_out };
  for (int l = 0; l < LAYERS; ++l) {
    node_gemm_kernel<<<NN / 16, 256, 0, stream>>>(
        xin, Wl + (size_t)l * 256 * 256, bl + l * 256,
        Wr + (size_t)l * 256 * 256, br + l * 256, xl, xr);
    edge_logits_kernel<<<(NEF + 63) / 64, 256, 0, stream>>>(
        eattr, lattr, ei, We + (size_t)l * 64 * 256, att + l * 256, xl, xr, logits);
    node_aggr_kernel<<<NN, 256, 0, stream>>>(
        logits, xl, offs, seid, ssrc, bias + l * 256, louts[l]);
    xin = louts[l];
  }
}

// Round 4
// 3048.544 us; speedup vs baseline: 1.8630x; 1.1429x over previous
//
#include <hip/hip_runtime.h>
#include <cstdint>

#define NN 50000
#define NE 800000
#define NEF (NE + NN)
#define NTILES (NEF / 16)   // 53125, exact
#define LAYERS 3
#define NEG_SLOPE 0.2f

typedef __bf16 bf16x8 __attribute__((ext_vector_type(8)));
typedef float f32x4 __attribute__((ext_vector_type(4)));

// ---------------- sort-by-dst machinery (runs once per call) ----------------

__global__ void hist_kernel(const int* __restrict__ ei, int* __restrict__ cnt) {
  int e = blockIdx.x * blockDim.x + threadIdx.x;
  if (e < NE) atomicAdd(&cnt[ei[NE + e]], 1);
}

__global__ void scan_kernel(const int* __restrict__ cnt, int* __restrict__ offs) {
  __shared__ int lds[1024];
  __shared__ int carry_s;
  int t = threadIdx.x;
  if (t == 0) carry_s = 0;
  __syncthreads();
  for (int base = 0; base < NN; base += 1024) {
    int i = base + t;
    int v = (i < NN) ? (cnt[i] + 1) : 0;   // +1 = self loop
    lds[t] = v;
    __syncthreads();
    for (int off = 1; off < 1024; off <<= 1) {
      int y = (t >= off) ? lds[t - off] : 0;
      __syncthreads();
      lds[t] += y;
      __syncthreads();
    }
    if (i < NN) offs[i] = carry_s + lds[t] - v;
    __syncthreads();
    if (t == 1023) carry_s += lds[1023];
    __syncthreads();
  }
  if (t == 0) offs[NN] = carry_s;
}

__global__ void scatter_kernel(const int* __restrict__ ei, const int* __restrict__ offs,
                               int* __restrict__ fill, int* __restrict__ seid, int* __restrict__ ssrc) {
  int e = blockIdx.x * blockDim.x + threadIdx.x;
  if (e >= NEF) return;
  int s, d;
  if (e < NE) { s = ei[e]; d = ei[NE + e]; }
  else        { s = d = e - NE; }
  int pos = offs[d] + atomicAdd(&fill[d], 1);
  seid[pos] = e;
  ssrc[pos] = s;
}

__global__ void loopattr_kernel(const float* __restrict__ eattr, const int* __restrict__ offs,
                                const int* __restrict__ seid, float* __restrict__ lattr) {
  int wv = threadIdx.x >> 6, lane = threadIdx.x & 63;
  int n = blockIdx.x * 4 + wv;
  if (n >= NN) return;
  int beg = offs[n], end = offs[n + 1];
  float acc = 0.f;
  int c = 0;
  for (int i = beg; i < end; ++i) {
    int eid = seid[i];
    if (eid < NE) { acc += eattr[(size_t)eid * 64 + lane]; c++; }
  }
  lattr[n * 64 + lane] = acc / (float)(c > 0 ? c : 1);
}

// We[l][64][256] f32 -> fragment-major bf16: wef[l][nt(16)][ks(2)][lane(64)][j(8)]
// element = We[l][ks*32 + (lane>>4)*8 + j][nt*16 + (lane&15)]
__global__ void wefrag_kernel(const float* __restrict__ We, __bf16* __restrict__ wef) {
  int idx = blockIdx.x * 256 + threadIdx.x;
  if (idx >= LAYERS * 16 * 2 * 64) return;
  int lane = idx & 63, ks = (idx >> 6) & 1, nt = (idx >> 7) & 15, l = idx >> 11;
  int col = nt * 16 + (lane & 15);
  int k0 = ks * 32 + (lane >> 4) * 8;
  const float* src = We + (((size_t)l * 64 + k0) * 256 + col);
  __bf16* dst = wef + (size_t)idx * 8;
  #pragma unroll
  for (int j = 0; j < 8; ++j) dst[j] = (__bf16)src[(size_t)j * 256];
}

// ---------------- per-layer kernels ----------------

__global__ void __launch_bounds__(256) node_gemm_kernel(
    const float* __restrict__ x, const float* __restrict__ Wl, const float* __restrict__ bl,
    const float* __restrict__ Wr, const float* __restrict__ br,
    float* __restrict__ xl, float* __restrict__ xr) {
  __shared__ float xs[16][256];
  int t = threadIdx.x;
  int row0 = blockIdx.x * 16;
  #pragma unroll
  for (int j = 0; j < 16; ++j) xs[j][t] = x[(row0 + j) * 256 + t];
  __syncthreads();
  float aL[16], aR[16];
  #pragma unroll
  for (int r = 0; r < 16; ++r) { aL[r] = 0.f; aR[r] = 0.f; }
  for (int k4 = 0; k4 < 64; ++k4) {
    int k = 4 * k4;
    float l0 = Wl[(k + 0) * 256 + t], l1 = Wl[(k + 1) * 256 + t];
    float l2 = Wl[(k + 2) * 256 + t], l3 = Wl[(k + 3) * 256 + t];
    float r0 = Wr[(k + 0) * 256 + t], r1 = Wr[(k + 1) * 256 + t];
    float r2 = Wr[(k + 2) * 256 + t], r3 = Wr[(k + 3) * 256 + t];
    #pragma unroll
    for (int r = 0; r < 16; ++r) {
      float4 xv = *reinterpret_cast<const float4*>(&xs[r][k]);
      aL[r] += xv.x * l0 + xv.y * l1 + xv.z * l2 + xv.w * l3;
      aR[r] += xv.x * r0 + xv.y * r1 + xv.z * r2 + xv.w * r3;
    }
  }
  float bL = bl[t], bR = br[t];
  #pragma unroll
  for (int r = 0; r < 16; ++r) {
    xl[(row0 + r) * 256 + t] = aL[r] + bL;
    xr[(row0 + r) * 256 + t] = aR[r] + bR;
  }
}

// MFMA edge kernel: ee[64,256] = eattr_blk[64,64] @ We[64,256] via 16x16x32 bf16,
// A-side hi/lo error compensation; fused gathers + leaky + att-dot + shfl reduce.
__global__ void __launch_bounds__(256) edge_logits_mfma(
    const float* __restrict__ eattr, const float* __restrict__ lattr,
    const int* __restrict__ ei, const __bf16* __restrict__ wef,
    const float* __restrict__ att, const float* __restrict__ xl,
    const float* __restrict__ xr, float* __restrict__ logits) {
  __shared__ __bf16 b_lds[16 * 2 * 64 * 8];   // 32 KB, fragment-major
  __shared__ int sidx[64], didx[64];
  int t = threadIdx.x, lane = t & 63, wv = t >> 6;
  int li = lane & 15, g = lane >> 4;
  int e0 = blockIdx.x * 64;

  if (t < 128) {
    int r = t & 63, e = e0 + r, v = 0;
    if (e < NE)       v = ei[(t < 64) ? e : (NE + e)];
    else if (e < NEF) v = e - NE;
    if (t < 64) sidx[r] = v; else didx[r] = v;
  }

  // stage We fragments: 2048 x 16B chunks, linear
  {
    const bf16x8* gb = (const bf16x8*)wef;
    bf16x8* lb = (bf16x8*)b_lds;
    #pragma unroll
    for (int i = 0; i < 8; ++i) lb[i * 256 + t] = gb[i * 256 + t];
  }
  __syncthreads();

  // B fragments for this wave's head (cols wv*64 .. +63)
  bf16x8 bfr[4][2];
  #pragma unroll
  for (int nt = 0; nt < 4; ++nt)
    #pragma unroll
    for (int ks = 0; ks < 2; ++ks)
      bfr[nt][ks] = ((const bf16x8*)b_lds)[(((wv * 4 + nt) * 2) + ks) * 64 + lane];

  f32x4 acc[4][4] = {};
  #pragma unroll
  for (int m = 0; m < 4; ++m) {
    int e = e0 + m * 16 + li;
    bool ok = e < NEF;
    const float* ap = ok ? ((e < NE) ? eattr + (size_t)e * 64
                                     : lattr + (size_t)(e - NE) * 64)
                         : eattr;
    bf16x8 ahi[2], alo[2];
    #pragma unroll
    for (int ks = 0; ks < 2; ++ks) {
      int k0 = ks * 32 + g * 8;
      float4 u = ok ? *reinterpret_cast<const float4*>(ap + k0)
                    : make_float4(0.f, 0.f, 0.f, 0.f);
      float4 w = ok ? *reinterpret_cast<const float4*>(ap + k0 + 4)
                    : make_float4(0.f, 0.f, 0.f, 0.f);
      float f[8] = {u.x, u.y, u.z, u.w, w.x, w.y, w.z, w.w};
      #pragma unroll
      for (int j = 0; j < 8; ++j) {
        __bf16 h = (__bf16)f[j];
        ahi[ks][j] = h;
        alo[ks][j] = (__bf16)(f[j] - (float)h);
      }
    }
    #pragma unroll
    for (int nt = 0; nt < 4; ++nt) {
      acc[m][nt] = __builtin_amdgcn_mfma_f32_16x16x32_bf16(ahi[0], bfr[nt][0], acc[m][nt], 0, 0, 0);
      acc[m][nt] = __builtin_amdgcn_mfma_f32_16x16x32_bf16(alo[0], bfr[nt][0], acc[m][nt], 0, 0, 0);
      acc[m][nt] = __builtin_amdgcn_mfma_f32_16x16x32_bf16(ahi[1], bfr[nt][1], acc[m][nt], 0, 0, 0);
      acc[m][nt] = __builtin_amdgcn_mfma_f32_16x16x32_bf16(alo[1], bfr[nt][1], acc[m][nt], 0, 0, 0);
    }
  }

  // tail: m[e,c] = ee + xl[s,c] + xr[d,c]; logits[e,wv] = sum_c leaky(m)*att[c]
  float attv[4];
  #pragma unroll
  for (int nt = 0; nt < 4; ++nt) attv[nt] = att[wv * 64 + nt * 16 + li];

  #pragma unroll
  for (int m = 0; m < 4; ++m) {
    #pragma unroll
    for (int r = 0; r < 4; ++r) {
      int row = m * 16 + g * 4 + r;
      int e = e0 + row;
      float nsum = 0.f;
      if (e < NEF) {
        int s = sidx[row], d = didx[row];
        #pragma unroll
        for (int nt = 0; nt < 4; ++nt) {
          int c = wv * 64 + nt * 16 + li;
          float mm = acc[m][nt][r] + xl[(size_t)s * 256 + c] + xr[(size_t)d * 256 + c];
          nsum += (fmaxf(mm, 0.f) + NEG_SLOPE * fminf(mm, 0.f)) * attv[nt];
        }
      }
      #pragma unroll
      for (int off = 8; off >= 1; off >>= 1) nsum += __shfl_xor(nsum, off, 64);
      if (li == 0 && e < NEF) logits[(size_t)e * 4 + wv] = nsum;
    }
  }
}

// Per-node segment softmax + weighted aggregation (+bias). One block per node.
__global__ void __launch_bounds__(256) node_aggr_kernel(
    const float* __restrict__ logits, const float* __restrict__ xl,
    const int* __restrict__ offs, const int* __restrict__ seid,
    const int* __restrict__ ssrc, const float* __restrict__ bias,
    float* __restrict__ out) {
  int n = blockIdx.x;
  int t = threadIdx.x;
  int h = t >> 6;
  int beg = offs[n], end = offs[n + 1];
  float mx = -1e30f;
  for (int i = beg; i < end; ++i) mx = fmaxf(mx, logits[seid[i] * 4 + h]);
  float den = 0.f;
  float acc = 0.f;
  for (int i = beg; i < end; ++i) {
    float a = expf(logits[seid[i] * 4 + h] - mx);
    den += a;
    acc += a * xl[(size_t)ssrc[i] * 256 + t];
  }
  out[n * 256 + t] = acc / den + bias[t];
}

// ---------------- host launcher ----------------

extern "C" void kernel_launch(void* const* d_in, const int* in_sizes, int n_in,
                              void* d_out, int out_size, void* d_ws, size_t ws_size,
                              hipStream_t stream) {
  (void)in_sizes; (void)n_in; (void)out_size; (void)ws_size;
  const float* x      = (const float*)d_in[0];
  const int* ei       = (const int*)d_in[1];
  const float* eattr  = (const float*)d_in[2];
  const float* Wl     = (const float*)d_in[3];
  const float* bl     = (const float*)d_in[4];
  const float* Wr     = (const float*)d_in[5];
  const float* br     = (const float*)d_in[6];
  const float* We     = (const float*)d_in[7];
  const float* att    = (const float*)d_in[8];
  const float* bias   = (const float*)d_in[9];

  size_t off = 0;
  char* base = (char*)d_ws;
  auto alloc = [&](size_t bytes) { void* p = base + off; off += (bytes + 255) & ~(size_t)255; return p; };
  float* xl     = (float*)alloc((size_t)NN * 256 * 4);
  float* xr     = (float*)alloc((size_t)NN * 256 * 4);
  float* bufA   = (float*)alloc((size_t)NN * 256 * 4);
  float* bufB   = (float*)alloc((size_t)NN * 256 * 4);
  float* logits = (float*)alloc((size_t)NEF * 4 * 4);
  float* lattr  = (float*)alloc((size_t)NN * 64 * 4);
  __bf16* wef   = (__bf16*)alloc((size_t)LAYERS * 16 * 2 * 64 * 8 * 2);
  int* seid     = (int*)alloc((size_t)NEF * 4);
  int* ssrc     = (int*)alloc((size_t)NEF * 4);
  int* offs     = (int*)alloc((size_t)(NN + 1) * 4);
  int* cnt      = (int*)alloc((size_t)NN * 4);
  int* fill     = (int*)alloc((size_t)NN * 4);

  hipMemsetAsync(cnt, 0, (size_t)NN * 4, stream);
  hipMemsetAsync(fill, 0, (size_t)NN * 4, stream);

  hist_kernel<<<(NE + 255) / 256, 256, 0, stream>>>(ei, cnt);
  scan_kernel<<<1, 1024, 0, stream>>>(cnt, offs);
  scatter_kernel<<<(NEF + 255) / 256, 256, 0, stream>>>(ei, offs, fill, seid, ssrc);
  loopattr_kernel<<<(NN + 3) / 4, 256, 0, stream>>>(eattr, offs, seid, lattr);
  wefrag_kernel<<<(LAYERS * 16 * 2 * 64 + 255) / 256, 256, 0, stream>>>(We, wef);

  const float* xin = x;
  float* louts[3] = { bufA, bufB, (float*)d_out };
  for (int l = 0; l < LAYERS; ++l) {
    node_gemm_kernel<<<NN / 16, 256, 0, stream>>>(
        xin, Wl + (size_t)l * 256 * 256, bl + l * 256,
        Wr + (size_t)l * 256 * 256, br + l * 256, xl, xr);
    edge_logits_mfma<<<(NEF + 63) / 64, 256, 0, stream>>>(
        eattr, lattr, ei, wef + (size_t)l * 16 * 2 * 64 * 8,
        att + l * 256, xl, xr, logits);
    node_aggr_kernel<<<NN, 256, 0, stream>>>(
        logits, xl, offs, seid, ssrc, bias + l * 256, louts[l]);
    xin = louts[l];
  }
}

// Round 5
// 2502.624 us; speedup vs baseline: 2.2694x; 1.2181x over previous
//
#include <hip/hip_runtime.h>
#include <cstdint>

#define NN 50000
#define NE 800000
#define NEF (NE + NN)
#define LAYERS 3
#define NEG_SLOPE 0.2f

typedef __bf16 bf16x8 __attribute__((ext_vector_type(8)));
typedef float f32x4 __attribute__((ext_vector_type(4)));

// ---------------- sort-by-dst machinery (runs once per call) ----------------

__global__ void hist_kernel(const int* __restrict__ ei, int* __restrict__ cnt) {
  int e = blockIdx.x * blockDim.x + threadIdx.x;
  if (e < NE) atomicAdd(&cnt[ei[NE + e]], 1);
}

// exclusive scan of (cnt[i]+1) over NN elements; single block, shfl-based
__global__ void scan_kernel(const int* __restrict__ cnt, int* __restrict__ offs) {
  __shared__ int wsum[16];
  __shared__ int carry_s;
  int t = threadIdx.x, lane = t & 63, wv = t >> 6;
  if (t == 0) carry_s = 0;
  __syncthreads();
  for (int base = 0; base < NN; base += 1024) {
    int i = base + t;
    int v = (i < NN) ? (cnt[i] + 1) : 0;   // +1 = self loop
    int x = v;
    #pragma unroll
    for (int off = 1; off < 64; off <<= 1) {
      int y = __shfl_up(x, off, 64);
      if (lane >= off) x += y;
    }
    if (lane == 63) wsum[wv] = x;
    __syncthreads();
    if (t < 16) {
      int w = wsum[t];
      #pragma unroll
      for (int off = 1; off < 16; off <<= 1) {
        int y = __shfl_up(w, off, 16);
        if (t >= off) w += y;
      }
      wsum[t] = w;   // inclusive scan of wave sums
    }
    __syncthreads();
    int carry = carry_s;
    int excl = (wv == 0) ? 0 : wsum[wv - 1];
    if (i < NN) offs[i] = carry + excl + x - v;
    int tot = wsum[15];
    __syncthreads();
    if (t == 0) carry_s = carry + tot;
    __syncthreads();
  }
  if (t == 0) offs[NN] = carry_s;
}

__global__ void scatter_kernel(const int* __restrict__ ei, const int* __restrict__ offs,
                               int* __restrict__ fill, int* __restrict__ seid,
                               int* __restrict__ ssrc, int* __restrict__ sdst) {
  int e = blockIdx.x * blockDim.x + threadIdx.x;
  if (e >= NEF) return;
  int s, d;
  if (e < NE) { s = ei[e]; d = ei[NE + e]; }
  else        { s = d = e - NE; }
  int pos = offs[d] + atomicAdd(&fill[d], 1);
  seid[pos] = e;
  ssrc[pos] = s;
  sdst[pos] = d;
}

__global__ void loopattr_kernel(const float* __restrict__ eattr, const int* __restrict__ offs,
                                const int* __restrict__ seid, float* __restrict__ lattr) {
  int wv = threadIdx.x >> 6, lane = threadIdx.x & 63;
  int n = blockIdx.x * 4 + wv;
  if (n >= NN) return;
  int beg = offs[n], end = offs[n + 1];
  float acc = 0.f;
  int c = 0;
  for (int i = beg; i < end; ++i) {
    int eid = seid[i];
    if (eid < NE) { acc += eattr[(size_t)eid * 64 + lane]; c++; }
  }
  lattr[n * 64 + lane] = acc / (float)(c > 0 ? c : 1);
}

// We[l][64][256] f32 -> fragment-major bf16: wef[l][nt(16)][ks(2)][lane(64)][j(8)]
// element = We[l][ks*32 + (lane>>4)*8 + j][nt*16 + (lane&15)]
__global__ void wefrag_kernel(const float* __restrict__ We, __bf16* __restrict__ wef) {
  int idx = blockIdx.x * 256 + threadIdx.x;
  if (idx >= LAYERS * 16 * 2 * 64) return;
  int lane = idx & 63, ks = (idx >> 6) & 1, nt = (idx >> 7) & 15, l = idx >> 11;
  int col = nt * 16 + (lane & 15);
  int k0 = ks * 32 + (lane >> 4) * 8;
  const float* src = We + (((size_t)l * 64 + k0) * 256 + col);
  __bf16* dst = wef + (size_t)idx * 8;
  #pragma unroll
  for (int j = 0; j < 8; ++j) dst[j] = (__bf16)src[(size_t)j * 256];
}

// ---------------- per-layer kernels ----------------

__global__ void __launch_bounds__(256) node_gemm_kernel(
    const float* __restrict__ x, const float* __restrict__ Wl, const float* __restrict__ bl,
    const float* __restrict__ Wr, const float* __restrict__ br,
    float* __restrict__ xl, float* __restrict__ xr) {
  __shared__ float xs[16][256];
  int t = threadIdx.x;
  int row0 = blockIdx.x * 16;
  #pragma unroll
  for (int j = 0; j < 16; ++j) xs[j][t] = x[(row0 + j) * 256 + t];
  __syncthreads();
  float aL[16], aR[16];
  #pragma unroll
  for (int r = 0; r < 16; ++r) { aL[r] = 0.f; aR[r] = 0.f; }
  for (int k4 = 0; k4 < 64; ++k4) {
    int k = 4 * k4;
    float l0 = Wl[(k + 0) * 256 + t], l1 = Wl[(k + 1) * 256 + t];
    float l2 = Wl[(k + 2) * 256 + t], l3 = Wl[(k + 3) * 256 + t];
    float r0 = Wr[(k + 0) * 256 + t], r1 = Wr[(k + 1) * 256 + t];
    float r2 = Wr[(k + 2) * 256 + t], r3 = Wr[(k + 3) * 256 + t];
    #pragma unroll
    for (int r = 0; r < 16; ++r) {
      float4 xv = *reinterpret_cast<const float4*>(&xs[r][k]);
      aL[r] += xv.x * l0 + xv.y * l1 + xv.z * l2 + xv.w * l3;
      aR[r] += xv.x * r0 + xv.y * r1 + xv.z * r2 + xv.w * r3;
    }
  }
  float bL = bl[t], bR = br[t];
  #pragma unroll
  for (int r = 0; r < 16; ++r) {
    xl[(row0 + r) * 256 + t] = aL[r] + bL;
    xr[(row0 + r) * 256 + t] = aR[r] + bR;
  }
}

// MFMA edge kernel over SORTED edge list (by dst): consecutive edges share dst
// -> xr row reads are L1 hits; logits written at sorted positions.
__global__ void __launch_bounds__(256) edge_logits_mfma(
    const float* __restrict__ eattr, const float* __restrict__ lattr,
    const int* __restrict__ ssrc, const int* __restrict__ sdst,
    const int* __restrict__ seid, const __bf16* __restrict__ wef,
    const float* __restrict__ att, const float* __restrict__ xl,
    const float* __restrict__ xr, float* __restrict__ logits) {
  __shared__ __bf16 b_lds[16 * 2 * 64 * 8];   // 32 KB, fragment-major
  __shared__ int sidx[64], didx[64], eidx[64];
  int t = threadIdx.x, lane = t & 63, wv = t >> 6;
  int li = lane & 15, g = lane >> 4;
  int p0 = blockIdx.x * 64;

  if (t < 64)       sidx[t] = ssrc[min(p0 + t, NEF - 1)];
  else if (t < 128) didx[t - 64] = sdst[min(p0 + t - 64, NEF - 1)];
  else if (t < 192) eidx[t - 128] = seid[min(p0 + t - 128, NEF - 1)];

  // stage We fragments: 2048 x 16B chunks, linear
  {
    const bf16x8* gb = (const bf16x8*)wef;
    bf16x8* lb = (bf16x8*)b_lds;
    #pragma unroll
    for (int i = 0; i < 8; ++i) lb[i * 256 + t] = gb[i * 256 + t];
  }
  __syncthreads();

  // B fragments for this wave's head (cols wv*64 .. +63)
  bf16x8 bfr[4][2];
  #pragma unroll
  for (int nt = 0; nt < 4; ++nt)
    #pragma unroll
    for (int ks = 0; ks < 2; ++ks)
      bfr[nt][ks] = ((const bf16x8*)b_lds)[(((wv * 4 + nt) * 2) + ks) * 64 + lane];

  f32x4 acc[4][4] = {};
  #pragma unroll
  for (int m = 0; m < 4; ++m) {
    int eid = eidx[m * 16 + li];
    const float* ap = (eid < NE) ? eattr + (size_t)eid * 64
                                 : lattr + (size_t)(eid - NE) * 64;
    bf16x8 ahi[2], alo[2];
    #pragma unroll
    for (int ks = 0; ks < 2; ++ks) {
      int k0 = ks * 32 + g * 8;
      float4 u = *reinterpret_cast<const float4*>(ap + k0);
      float4 w = *reinterpret_cast<const float4*>(ap + k0 + 4);
      float f[8] = {u.x, u.y, u.z, u.w, w.x, w.y, w.z, w.w};
      #pragma unroll
      for (int j = 0; j < 8; ++j) {
        __bf16 h = (__bf16)f[j];
        ahi[ks][j] = h;
        alo[ks][j] = (__bf16)(f[j] - (float)h);
      }
    }
    #pragma unroll
    for (int nt = 0; nt < 4; ++nt) {
      acc[m][nt] = __builtin_amdgcn_mfma_f32_16x16x32_bf16(ahi[0], bfr[nt][0], acc[m][nt], 0, 0, 0);
      acc[m][nt] = __builtin_amdgcn_mfma_f32_16x16x32_bf16(alo[0], bfr[nt][0], acc[m][nt], 0, 0, 0);
      acc[m][nt] = __builtin_amdgcn_mfma_f32_16x16x32_bf16(ahi[1], bfr[nt][1], acc[m][nt], 0, 0, 0);
      acc[m][nt] = __builtin_amdgcn_mfma_f32_16x16x32_bf16(alo[1], bfr[nt][1], acc[m][nt], 0, 0, 0);
    }
  }

  // tail: m[p,c] = ee + xl[s,c] + xr[d,c]; logits[p,wv] = sum_c leaky(m)*att[c]
  float attv[4];
  #pragma unroll
  for (int nt = 0; nt < 4; ++nt) attv[nt] = att[wv * 64 + nt * 16 + li];

  #pragma unroll
  for (int m = 0; m < 4; ++m) {
    #pragma unroll
    for (int r = 0; r < 4; ++r) {
      int row = m * 16 + g * 4 + r;
      int p = p0 + row;
      int s = sidx[row], d = didx[row];
      float nsum = 0.f;
      #pragma unroll
      for (int nt = 0; nt < 4; ++nt) {
        int c = wv * 64 + nt * 16 + li;
        float mm = acc[m][nt][r] + xl[(size_t)s * 256 + c] + xr[(size_t)d * 256 + c];
        nsum += (fmaxf(mm, 0.f) + NEG_SLOPE * fminf(mm, 0.f)) * attv[nt];
      }
      #pragma unroll
      for (int off = 8; off >= 1; off >>= 1) nsum += __shfl_xor(nsum, off, 64);
      if (li == 0 && p < NEF) logits[(size_t)p * 4 + wv] = nsum;
    }
  }
}

// Segment softmax + aggregation: ONE WAVE per node; lane owns 4 channels.
__global__ void __launch_bounds__(256) node_aggr_kernel(
    const float* __restrict__ logits, const float* __restrict__ xl,
    const int* __restrict__ offs, const int* __restrict__ ssrc,
    const float* __restrict__ bias, float* __restrict__ out) {
  int wv = threadIdx.x >> 6, lane = threadIdx.x & 63;
  int n = blockIdx.x * 4 + wv;
  if (n >= NN) return;
  int h = lane >> 4;                 // head of this lane's 4 channels
  int beg = offs[n], end = offs[n + 1];
  float mx = -1e30f;
  for (int i = beg; i < end; ++i) mx = fmaxf(mx, logits[(size_t)i * 4 + h]);
  const float4* xl4 = (const float4*)xl;
  float4 acc = make_float4(0.f, 0.f, 0.f, 0.f);
  float den = 0.f;
  for (int i = beg; i < end; ++i) {
    float a = expf(logits[(size_t)i * 4 + h] - mx);
    den += a;
    float4 f = xl4[(size_t)ssrc[i] * 64 + lane];
    acc.x += a * f.x; acc.y += a * f.y; acc.z += a * f.z; acc.w += a * f.w;
  }
  float inv = 1.f / den;
  float4 b = ((const float4*)bias)[lane];
  float4 o = make_float4(acc.x * inv + b.x, acc.y * inv + b.y,
                         acc.z * inv + b.z, acc.w * inv + b.w);
  ((float4*)out)[(size_t)n * 64 + lane] = o;
}

// ---------------- host launcher ----------------

extern "C" void kernel_launch(void* const* d_in, const int* in_sizes, int n_in,
                              void* d_out, int out_size, void* d_ws, size_t ws_size,
                              hipStream_t stream) {
  (void)in_sizes; (void)n_in; (void)out_size; (void)ws_size;
  const float* x      = (const float*)d_in[0];
  const int* ei       = (const int*)d_in[1];
  const float* eattr  = (const float*)d_in[2];
  const float* Wl     = (const float*)d_in[3];
  const float* bl     = (const float*)d_in[4];
  const float* Wr     = (const float*)d_in[5];
  const float* br     = (const float*)d_in[6];
  const float* We     = (const float*)d_in[7];
  const float* att    = (const float*)d_in[8];
  const float* bias   = (const float*)d_in[9];

  size_t off = 0;
  char* base = (char*)d_ws;
  auto alloc = [&](size_t bytes) { void* p = base + off; off += (bytes + 255) & ~(size_t)255; return p; };
  float* xl     = (float*)alloc((size_t)NN * 256 * 4);
  float* xr     = (float*)alloc((size_t)NN * 256 * 4);
  float* bufA   = (float*)alloc((size_t)NN * 256 * 4);
  float* bufB   = (float*)alloc((size_t)NN * 256 * 4);
  float* logits = (float*)alloc((size_t)NEF * 4 * 4);
  float* lattr  = (float*)alloc((size_t)NN * 64 * 4);
  __bf16* wef   = (__bf16*)alloc((size_t)LAYERS * 16 * 2 * 64 * 8 * 2);
  int* seid     = (int*)alloc((size_t)NEF * 4);
  int* ssrc     = (int*)alloc((size_t)NEF * 4);
  int* sdst     = (int*)alloc((size_t)NEF * 4);
  int* offs     = (int*)alloc((size_t)(NN + 1) * 4);
  int* cnt      = (int*)alloc((size_t)NN * 4);
  int* fill     = (int*)alloc((size_t)NN * 4);

  hipMemsetAsync(cnt, 0, (size_t)NN * 4, stream);
  hipMemsetAsync(fill, 0, (size_t)NN * 4, stream);

  hist_kernel<<<(NE + 255) / 256, 256, 0, stream>>>(ei, cnt);
  scan_kernel<<<1, 1024, 0, stream>>>(cnt, offs);
  scatter_kernel<<<(NEF + 255) / 256, 256, 0, stream>>>(ei, offs, fill, seid, ssrc, sdst);
  loopattr_kernel<<<(NN + 3) / 4, 256, 0, stream>>>(eattr, offs, seid, lattr);
  wefrag_kernel<<<(LAYERS * 16 * 2 * 64 + 255) / 256, 256, 0, stream>>>(We, wef);

  const float* xin = x;
  float* louts[3] = { bufA, bufB, (float*)d_out };
  for (int l = 0; l < LAYERS; ++l) {
    node_gemm_kernel<<<NN / 16, 256, 0, stream>>>(
        xin, Wl + (size_t)l * 256 * 256, bl + l * 256,
        Wr + (size_t)l * 256 * 256, br + l * 256, xl, xr);
    edge_logits_mfma<<<(NEF + 63) / 64, 256, 0, stream>>>(
        eattr, lattr, ssrc, sdst, seid, wef + (size_t)l * 16 * 2 * 64 * 8,
        att + l * 256, xl, xr, logits);
    node_aggr_kernel<<<(NN + 3) / 4, 256, 0, stream>>>(
        logits, xl, offs, ssrc, bias + l * 256, louts[l]);
    xin = louts[l];
  }
}

// Round 6
// 2123.604 us; speedup vs baseline: 2.6744x; 1.1785x over previous
//
#include <hip/hip_runtime.h>
#include <cstdint>

#define NN 50000
#define NE 800000
#define NEF (NE + NN)
#define NTILES (NEF / 16)   // 53125, exact
#define LAYERS 3
#define NEG_SLOPE 0.2f

typedef __bf16 bf16x8 __attribute__((ext_vector_type(8)));
typedef float f32x4 __attribute__((ext_vector_type(4)));

// ---------------- sort-by-dst machinery (runs once per call) ----------------

__global__ void hist_kernel(const int* __restrict__ ei, int* __restrict__ cnt) {
  int e = blockIdx.x * blockDim.x + threadIdx.x;
  if (e < NE) atomicAdd(&cnt[ei[NE + e]], 1);
}

// exclusive scan of (cnt[i]+1) over NN elements; single block, shfl-based
__global__ void scan_kernel(const int* __restrict__ cnt, int* __restrict__ offs) {
  __shared__ int wsum[16];
  __shared__ int carry_s;
  int t = threadIdx.x, lane = t & 63, wv = t >> 6;
  if (t == 0) carry_s = 0;
  __syncthreads();
  for (int base = 0; base < NN; base += 1024) {
    int i = base + t;
    int v = (i < NN) ? (cnt[i] + 1) : 0;   // +1 = self loop
    int x = v;
    #pragma unroll
    for (int off = 1; off < 64; off <<= 1) {
      int y = __shfl_up(x, off, 64);
      if (lane >= off) x += y;
    }
    if (lane == 63) wsum[wv] = x;
    __syncthreads();
    if (t < 16) {
      int w = wsum[t];
      #pragma unroll
      for (int off = 1; off < 16; off <<= 1) {
        int y = __shfl_up(w, off, 16);
        if (t >= off) w += y;
      }
      wsum[t] = w;   // inclusive scan of wave sums
    }
    __syncthreads();
    int carry = carry_s;
    int excl = (wv == 0) ? 0 : wsum[wv - 1];
    if (i < NN) offs[i] = carry + excl + x - v;
    int tot = wsum[15];
    __syncthreads();
    if (t == 0) carry_s = carry + tot;
    __syncthreads();
  }
  if (t == 0) offs[NN] = carry_s;
}

__global__ void scatter_kernel(const int* __restrict__ ei, const int* __restrict__ offs,
                               int* __restrict__ fill, int* __restrict__ seid,
                               int* __restrict__ ssrc, int* __restrict__ sdst) {
  int e = blockIdx.x * blockDim.x + threadIdx.x;
  if (e >= NEF) return;
  int s, d;
  if (e < NE) { s = ei[e]; d = ei[NE + e]; }
  else        { s = d = e - NE; }
  int pos = offs[d] + atomicAdd(&fill[d], 1);
  seid[pos] = e;
  ssrc[pos] = s;
  sdst[pos] = d;
}

__global__ void loopattr_kernel(const float* __restrict__ eattr, const int* __restrict__ offs,
                                const int* __restrict__ seid, float* __restrict__ lattr) {
  int wv = threadIdx.x >> 6, lane = threadIdx.x & 63;
  int n = blockIdx.x * 4 + wv;
  if (n >= NN) return;
  int beg = offs[n], end = offs[n + 1];
  float acc = 0.f;
  int c = 0;
  for (int i = beg; i < end; ++i) {
    int eid = seid[i];
    if (eid < NE) { acc += eattr[(size_t)eid * 64 + lane]; c++; }
  }
  lattr[n * 64 + lane] = acc / (float)(c > 0 ? c : 1);
}

// We[l][64][256] f32 -> fragment-major bf16: wef[l][nt(16)][ks(2)][lane(64)][j(8)]
// element = We[l][ks*32 + (lane>>4)*8 + j][nt*16 + (lane&15)]
__global__ void wefrag_kernel(const float* __restrict__ We, __bf16* __restrict__ wef) {
  int idx = blockIdx.x * 256 + threadIdx.x;
  if (idx >= LAYERS * 16 * 2 * 64) return;
  int lane = idx & 63, ks = (idx >> 6) & 1, nt = (idx >> 7) & 15, l = idx >> 11;
  int col = nt * 16 + (lane & 15);
  int k0 = ks * 32 + (lane >> 4) * 8;
  const float* src = We + (((size_t)l * 64 + k0) * 256 + col);
  __bf16* dst = wef + (size_t)idx * 8;
  #pragma unroll
  for (int j = 0; j < 8; ++j) dst[j] = (__bf16)src[(size_t)j * 256];
}

// A-fragments in dst-sorted order, bf16 hi/lo, fragment-major:
// afrag[tile][ks(2)][p(2: hi,lo)][lane(64)][j(8)];
// element = row li=lane&15 of tile (sorted pos tile*16+li), k = ks*32+(lane>>4)*8+j
__global__ void afrag_kernel(const float* __restrict__ eattr, const float* __restrict__ lattr,
                             const int* __restrict__ seid, __bf16* __restrict__ afrag) {
  int idx = blockIdx.x * 256 + threadIdx.x;
  if (idx >= NTILES * 64) return;
  int lane = idx & 63, tile = idx >> 6;
  int li = lane & 15, g = lane >> 4;
  int eid = seid[tile * 16 + li];
  const float* ap = (eid < NE) ? eattr + (size_t)eid * 64
                               : lattr + (size_t)(eid - NE) * 64;
  #pragma unroll
  for (int ks = 0; ks < 2; ++ks) {
    int k0 = ks * 32 + g * 8;
    float4 u = *reinterpret_cast<const float4*>(ap + k0);
    float4 w = *reinterpret_cast<const float4*>(ap + k0 + 4);
    float f[8] = {u.x, u.y, u.z, u.w, w.x, w.y, w.z, w.w};
    bf16x8 hi, lo;
    #pragma unroll
    for (int j = 0; j < 8; ++j) {
      __bf16 h = (__bf16)f[j];
      hi[j] = h;
      lo[j] = (__bf16)(f[j] - (float)h);
    }
    bf16x8* dst = (bf16x8*)afrag;
    dst[(((size_t)tile * 2 + ks) * 2 + 0) * 64 + lane] = hi;
    dst[(((size_t)tile * 2 + ks) * 2 + 1) * 64 + lane] = lo;
  }
}

// ---------------- per-layer kernels ----------------

__global__ void __launch_bounds__(256) node_gemm_kernel(
    const float* __restrict__ x, const float* __restrict__ Wl, const float* __restrict__ bl,
    const float* __restrict__ Wr, const float* __restrict__ br,
    float* __restrict__ xl, float* __restrict__ xr) {
  __shared__ float xs[16][256];
  int t = threadIdx.x;
  int row0 = blockIdx.x * 16;
  #pragma unroll
  for (int j = 0; j < 16; ++j) xs[j][t] = x[(row0 + j) * 256 + t];
  __syncthreads();
  float aL[16], aR[16];
  #pragma unroll
  for (int r = 0; r < 16; ++r) { aL[r] = 0.f; aR[r] = 0.f; }
  for (int k4 = 0; k4 < 64; ++k4) {
    int k = 4 * k4;
    float l0 = Wl[(k + 0) * 256 + t], l1 = Wl[(k + 1) * 256 + t];
    float l2 = Wl[(k + 2) * 256 + t], l3 = Wl[(k + 3) * 256 + t];
    float r0 = Wr[(k + 0) * 256 + t], r1 = Wr[(k + 1) * 256 + t];
    float r2 = Wr[(k + 2) * 256 + t], r3 = Wr[(k + 3) * 256 + t];
    #pragma unroll
    for (int r = 0; r < 16; ++r) {
      float4 xv = *reinterpret_cast<const float4*>(&xs[r][k]);
      aL[r] += xv.x * l0 + xv.y * l1 + xv.z * l2 + xv.w * l3;
      aR[r] += xv.x * r0 + xv.y * r1 + xv.z * r2 + xv.w * r3;
    }
  }
  float bL = bl[t], bR = br[t];
  #pragma unroll
  for (int r = 0; r < 16; ++r) {
    xl[(row0 + r) * 256 + t] = aL[r] + bL;
    xr[(row0 + r) * 256 + t] = aR[r] + bR;
  }
}

// Fast MFMA edge kernel: A-fragments pre-staged (afrag), B direct from L2, tiny LDS.
__global__ void __launch_bounds__(256) edge_logits_fast(
    const __bf16* __restrict__ afrag, const int* __restrict__ ssrc,
    const int* __restrict__ sdst, const __bf16* __restrict__ wef,
    const float* __restrict__ att, const float* __restrict__ xl,
    const float* __restrict__ xr, float* __restrict__ logits) {
  __shared__ int sidx[64], didx[64];
  int t = threadIdx.x, lane = t & 63, wv = t >> 6;
  int li = lane & 15, g = lane >> 4;
  int p0 = blockIdx.x * 64;

  if (t < 64)       sidx[t] = ssrc[min(p0 + t, NEF - 1)];
  else if (t < 128) didx[t - 64] = sdst[min(p0 + t - 64, NEF - 1)];
  __syncthreads();

  // B fragments for this wave's head (cols wv*64 .. +63), straight from global/L2
  const bf16x8* gb = (const bf16x8*)wef;
  bf16x8 bfr[4][2];
  #pragma unroll
  for (int nt = 0; nt < 4; ++nt)
    #pragma unroll
    for (int ks = 0; ks < 2; ++ks)
      bfr[nt][ks] = gb[(((wv * 4 + nt) * 2) + ks) * 64 + lane];

  const bf16x8* ga = (const bf16x8*)afrag;
  f32x4 acc[4][4] = {};
  #pragma unroll
  for (int m = 0; m < 4; ++m) {
    int tile = min(blockIdx.x * 4 + m, NTILES - 1);
    size_t tb = (size_t)tile * 256;   // 4 KB per tile = 256 bf16x8
    bf16x8 ahi0 = ga[tb + (0 * 2 + 0) * 64 + lane];
    bf16x8 alo0 = ga[tb + (0 * 2 + 1) * 64 + lane];
    bf16x8 ahi1 = ga[tb + (1 * 2 + 0) * 64 + lane];
    bf16x8 alo1 = ga[tb + (1 * 2 + 1) * 64 + lane];
    #pragma unroll
    for (int nt = 0; nt < 4; ++nt) {
      acc[m][nt] = __builtin_amdgcn_mfma_f32_16x16x32_bf16(ahi0, bfr[nt][0], acc[m][nt], 0, 0, 0);
      acc[m][nt] = __builtin_amdgcn_mfma_f32_16x16x32_bf16(alo0, bfr[nt][0], acc[m][nt], 0, 0, 0);
      acc[m][nt] = __builtin_amdgcn_mfma_f32_16x16x32_bf16(ahi1, bfr[nt][1], acc[m][nt], 0, 0, 0);
      acc[m][nt] = __builtin_amdgcn_mfma_f32_16x16x32_bf16(alo1, bfr[nt][1], acc[m][nt], 0, 0, 0);
    }
  }

  float attv[4];
  #pragma unroll
  for (int nt = 0; nt < 4; ++nt) attv[nt] = att[wv * 64 + nt * 16 + li];

  #pragma unroll
  for (int m = 0; m < 4; ++m) {
    #pragma unroll
    for (int r = 0; r < 4; ++r) {
      int row = m * 16 + g * 4 + r;
      int p = p0 + row;
      int s = sidx[row], d = didx[row];
      float nsum = 0.f;
      #pragma unroll
      for (int nt = 0; nt < 4; ++nt) {
        int c = wv * 64 + nt * 16 + li;
        float mm = acc[m][nt][r] + xl[(size_t)s * 256 + c] + xr[(size_t)d * 256 + c];
        nsum += (fmaxf(mm, 0.f) + NEG_SLOPE * fminf(mm, 0.f)) * attv[nt];
      }
      #pragma unroll
      for (int off = 8; off >= 1; off >>= 1) nsum += __shfl_xor(nsum, off, 64);
      if (li == 0 && p < NEF) logits[(size_t)p * 4 + wv] = nsum;
    }
  }
}

// Fallback (ws too small for afrag): round-5 variant with per-layer gather+convert.
__global__ void __launch_bounds__(256) edge_logits_gather(
    const float* __restrict__ eattr, const float* __restrict__ lattr,
    const int* __restrict__ ssrc, const int* __restrict__ sdst,
    const int* __restrict__ seid, const __bf16* __restrict__ wef,
    const float* __restrict__ att, const float* __restrict__ xl,
    const float* __restrict__ xr, float* __restrict__ logits) {
  __shared__ int sidx[64], didx[64], eidx[64];
  int t = threadIdx.x, lane = t & 63, wv = t >> 6;
  int li = lane & 15, g = lane >> 4;
  int p0 = blockIdx.x * 64;

  if (t < 64)       sidx[t] = ssrc[min(p0 + t, NEF - 1)];
  else if (t < 128) didx[t - 64] = sdst[min(p0 + t - 64, NEF - 1)];
  else if (t < 192) eidx[t - 128] = seid[min(p0 + t - 128, NEF - 1)];
  __syncthreads();

  const bf16x8* gb = (const bf16x8*)wef;
  bf16x8 bfr[4][2];
  #pragma unroll
  for (int nt = 0; nt < 4; ++nt)
    #pragma unroll
    for (int ks = 0; ks < 2; ++ks)
      bfr[nt][ks] = gb[(((wv * 4 + nt) * 2) + ks) * 64 + lane];

  f32x4 acc[4][4] = {};
  #pragma unroll
  for (int m = 0; m < 4; ++m) {
    int eid = eidx[m * 16 + li];
    const float* ap = (eid < NE) ? eattr + (size_t)eid * 64
                                 : lattr + (size_t)(eid - NE) * 64;
    bf16x8 ahi[2], alo[2];
    #pragma unroll
    for (int ks = 0; ks < 2; ++ks) {
      int k0 = ks * 32 + g * 8;
      float4 u = *reinterpret_cast<const float4*>(ap + k0);
      float4 w = *reinterpret_cast<const float4*>(ap + k0 + 4);
      float f[8] = {u.x, u.y, u.z, u.w, w.x, w.y, w.z, w.w};
      #pragma unroll
      for (int j = 0; j < 8; ++j) {
        __bf16 h = (__bf16)f[j];
        ahi[ks][j] = h;
        alo[ks][j] = (__bf16)(f[j] - (float)h);
      }
    }
    #pragma unroll
    for (int nt = 0; nt < 4; ++nt) {
      acc[m][nt] = __builtin_amdgcn_mfma_f32_16x16x32_bf16(ahi[0], bfr[nt][0], acc[m][nt], 0, 0, 0);
      acc[m][nt] = __builtin_amdgcn_mfma_f32_16x16x32_bf16(alo[0], bfr[nt][0], acc[m][nt], 0, 0, 0);
      acc[m][nt] = __builtin_amdgcn_mfma_f32_16x16x32_bf16(ahi[1], bfr[nt][1], acc[m][nt], 0, 0, 0);
      acc[m][nt] = __builtin_amdgcn_mfma_f32_16x16x32_bf16(alo[1], bfr[nt][1], acc[m][nt], 0, 0, 0);
    }
  }

  float attv[4];
  #pragma unroll
  for (int nt = 0; nt < 4; ++nt) attv[nt] = att[wv * 64 + nt * 16 + li];

  #pragma unroll
  for (int m = 0; m < 4; ++m) {
    #pragma unroll
    for (int r = 0; r < 4; ++r) {
      int row = m * 16 + g * 4 + r;
      int p = p0 + row;
      int s = sidx[row], d = didx[row];
      float nsum = 0.f;
      #pragma unroll
      for (int nt = 0; nt < 4; ++nt) {
        int c = wv * 64 + nt * 16 + li;
        float mm = acc[m][nt][r] + xl[(size_t)s * 256 + c] + xr[(size_t)d * 256 + c];
        nsum += (fmaxf(mm, 0.f) + NEG_SLOPE * fminf(mm, 0.f)) * attv[nt];
      }
      #pragma unroll
      for (int off = 8; off >= 1; off >>= 1) nsum += __shfl_xor(nsum, off, 64);
      if (li == 0 && p < NEF) logits[(size_t)p * 4 + wv] = nsum;
    }
  }
}

// Segment softmax + aggregation: ONE WAVE per node; lane owns 4 channels.
__global__ void __launch_bounds__(256) node_aggr_kernel(
    const float* __restrict__ logits, const float* __restrict__ xl,
    const int* __restrict__ offs, const int* __restrict__ ssrc,
    const float* __restrict__ bias, float* __restrict__ out) {
  int wv = threadIdx.x >> 6, lane = threadIdx.x & 63;
  int n = blockIdx.x * 4 + wv;
  if (n >= NN) return;
  int h = lane >> 4;                 // head of this lane's 4 channels
  int beg = offs[n], end = offs[n + 1];
  float mx = -1e30f;
  for (int i = beg; i < end; ++i) mx = fmaxf(mx, logits[(size_t)i * 4 + h]);
  const float4* xl4 = (const float4*)xl;
  float4 acc = make_float4(0.f, 0.f, 0.f, 0.f);
  float den = 0.f;
  for (int i = beg; i < end; ++i) {
    float a = expf(logits[(size_t)i * 4 + h] - mx);
    den += a;
    float4 f = xl4[(size_t)ssrc[i] * 64 + lane];
    acc.x += a * f.x; acc.y += a * f.y; acc.z += a * f.z; acc.w += a * f.w;
  }
  float inv = 1.f / den;
  float4 b = ((const float4*)bias)[lane];
  float4 o = make_float4(acc.x * inv + b.x, acc.y * inv + b.y,
                         acc.z * inv + b.z, acc.w * inv + b.w);
  ((float4*)out)[(size_t)n * 64 + lane] = o;
}

// ---------------- host launcher ----------------

extern "C" void kernel_launch(void* const* d_in, const int* in_sizes, int n_in,
                              void* d_out, int out_size, void* d_ws, size_t ws_size,
                              hipStream_t stream) {
  (void)in_sizes; (void)n_in; (void)out_size;
  const float* x      = (const float*)d_in[0];
  const int* ei       = (const int*)d_in[1];
  const float* eattr  = (const float*)d_in[2];
  const float* Wl     = (const float*)d_in[3];
  const float* bl     = (const float*)d_in[4];
  const float* Wr     = (const float*)d_in[5];
  const float* br     = (const float*)d_in[6];
  const float* We     = (const float*)d_in[7];
  const float* att    = (const float*)d_in[8];
  const float* bias   = (const float*)d_in[9];

  size_t off = 0;
  char* base = (char*)d_ws;
  auto alloc = [&](size_t bytes) { void* p = base + off; off += (bytes + 255) & ~(size_t)255; return p; };
  float* xl     = (float*)alloc((size_t)NN * 256 * 4);
  float* xr     = (float*)alloc((size_t)NN * 256 * 4);
  float* bufA   = (float*)alloc((size_t)NN * 256 * 4);
  float* bufB   = (float*)alloc((size_t)NN * 256 * 4);
  float* logits = (float*)alloc((size_t)NEF * 4 * 4);
  float* lattr  = (float*)alloc((size_t)NN * 64 * 4);
  __bf16* wef   = (__bf16*)alloc((size_t)LAYERS * 16 * 2 * 64 * 8 * 2);
  int* seid     = (int*)alloc((size_t)NEF * 4);
  int* ssrc     = (int*)alloc((size_t)NEF * 4);
  int* sdst     = (int*)alloc((size_t)NEF * 4);
  int* offs     = (int*)alloc((size_t)(NN + 1) * 4);
  int* cnt      = (int*)alloc((size_t)NN * 4);
  int* fill     = (int*)alloc((size_t)NN * 4);
  __bf16* afrag = (__bf16*)alloc((size_t)NTILES * 4096);
  bool use_afrag = off <= ws_size;

  hipMemsetAsync(cnt, 0, (size_t)NN * 4, stream);
  hipMemsetAsync(fill, 0, (size_t)NN * 4, stream);

  hist_kernel<<<(NE + 255) / 256, 256, 0, stream>>>(ei, cnt);
  scan_kernel<<<1, 1024, 0, stream>>>(cnt, offs);
  scatter_kernel<<<(NEF + 255) / 256, 256, 0, stream>>>(ei, offs, fill, seid, ssrc, sdst);
  loopattr_kernel<<<(NN + 3) / 4, 256, 0, stream>>>(eattr, offs, seid, lattr);
  wefrag_kernel<<<(LAYERS * 16 * 2 * 64 + 255) / 256, 256, 0, stream>>>(We, wef);
  if (use_afrag)
    afrag_kernel<<<(NTILES * 64 + 255) / 256, 256, 0, stream>>>(eattr, lattr, seid, afrag);

  const float* xin = x;
  float* louts[3] = { bufA, bufB, (float*)d_out };
  for (int l = 0; l < LAYERS; ++l) {
    node_gemm_kernel<<<NN / 16, 256, 0, stream>>>(
        xin, Wl + (size_t)l * 256 * 256, bl + l * 256,
        Wr + (size_t)l * 256 * 256, br + l * 256, xl, xr);
    if (use_afrag)
      edge_logits_fast<<<(NTILES + 3) / 4, 256, 0, stream>>>(
          afrag, ssrc, sdst, wef + (size_t)l * 16 * 2 * 64 * 8,
          att + l * 256, xl, xr, logits);
    else
      edge_logits_gather<<<(NTILES + 3) / 4, 256, 0, stream>>>(
          eattr, lattr, ssrc, sdst, seid, wef + (size_t)l * 16 * 2 * 64 * 8,
          att + l * 256, xl, xr, logits);
    node_aggr_kernel<<<(NN + 3) / 4, 256, 0, stream>>>(
        logits, xl, offs, ssrc, bias + l * 256, louts[l]);
    xin = louts[l];
  }
}